// Round 3
// baseline (3268.978 us; speedup 1.0000x reference)
//
#include <hip/hip_runtime.h>

#define S_LEN 512
#define B_SZ  32
#define H_SZ  1024
#define NG    4096      // 4H
#define K_SZ  1024
#define GWG   128       // consumer (recurrence) workgroups
#define PWG   96        // producer (GEMM) workgroups
#define SENT32 0xFFC0FFC0u   // bf16 NaN pair: unreachable for h in (-1,1)

typedef __attribute__((ext_vector_type(8))) short short8;
typedef __attribute__((ext_vector_type(4))) float floatx4;
typedef __attribute__((ext_vector_type(4))) unsigned short ushort4v;
typedef __attribute__((ext_vector_type(4))) unsigned int uintx4;

// ---------------- helpers ----------------
__device__ __forceinline__ unsigned short f2bf(float f){
  unsigned u = __float_as_uint(f);
  u += 0x7fffu + ((u >> 16) & 1u);     // RNE; inputs are finite/normal
  return (unsigned short)(u >> 16);
}
__device__ __forceinline__ float bf2f(unsigned short u){
  return __uint_as_float(((unsigned)u) << 16);
}
__device__ __forceinline__ float sigm(float x){ return 1.f / (1.f + __expf(-x)); }
__device__ __forceinline__ float tanh_f(float x){
  float ax = fabsf(x);
  float e = __expf(-2.f * ax);
  float r = (1.f - e) / (1.f + e);
  return copysignf(r, x);
}

// ---------------- fp32 -> bf16 conversion ----------------
__global__ __launch_bounds__(256) void cvt_bf16(const float* __restrict__ s,
                                                unsigned short* __restrict__ d, int n){
  int i = (blockIdx.x * 256 + threadIdx.x) * 4;
  if (i < n){
    float4 v = *(const float4*)(s + i);
    ushort4v o; o.x = f2bf(v.x); o.y = f2bf(v.y); o.z = f2bf(v.z); o.w = f2bf(v.w);
    *(ushort4v*)(d + i) = o;
  }
}

// sentinel-fill h history slots 1..512 (32 MB). Plain stores; L2 flushed at kernel end.
__global__ __launch_bounds__(256) void fill_sent(unsigned short* __restrict__ hh){
  size_t i = 32768 + ((size_t)blockIdx.x * 256 + threadIdx.x) * 8;  // grid covers 512*32768
  uintx4 v; v[0] = SENT32; v[1] = SENT32; v[2] = SENT32; v[3] = SENT32;
  *(uintx4*)(hh + i) = v;
}

// h0 -> bf16 into hist[0], zero gates-ready counters
__global__ __launch_bounds__(256) void cvt_h0(const float* __restrict__ s,
                                              unsigned short* __restrict__ d,
                                              unsigned* __restrict__ flags){
  int i = (blockIdx.x * 256 + threadIdx.x) * 4;   // grid covers exactly 32768
  float4 v = *(const float4*)(s + i);
  ushort4v o; o.x = f2bf(v.x); o.y = f2bf(v.y); o.z = f2bf(v.z); o.w = f2bf(v.w);
  *(ushort4v*)(d + i) = o;
  if (blockIdx.x == 0){
    flags[512 + threadIdx.x] = 0u;     // gp_cnt (128 uints) + slack
  }
}

// ---------------- fused persistent kernel ----------------
// WGs [0,128): LSTM recurrence (1/CU). WGs [128,224): Phase-A GEMM producers.
// h exchange: sentinel-validated speculative loads — no flags, no publisher ack.
#define LPAD 1032
#define GPADW 36   // gatesS row stride (floats): 2-way max bank alias (free per m136)
__global__ __launch_bounds__(256) void fused(const short* __restrict__ Xb,
                                             const short* __restrict__ Ub,
                                             unsigned short* __restrict__ gates_pre,
                                             const short* __restrict__ Vb,
                                             const float* __restrict__ bih,
                                             const float* __restrict__ bhh,
                                             const float* __restrict__ c0,
                                             unsigned short* __restrict__ hh,   // hist: 513 x 32768 bf16
                                             unsigned* __restrict__ gp_cnt,     // 128 uints
                                             float* __restrict__ out){
  __shared__ alignas(16) char smem[136704];
  const int tid = threadIdx.x;
  const int wave = tid >> 6, lane = tid & 63;
  const int ml = lane & 15, lg = lane >> 4;

  if (blockIdx.x >= GWG){
    // ================= producer: gates_pre[M=16384,4096] = Xb @ Ub^T =================
    short* As = (short*)smem;                  // 128*32 shorts
    short* Bs = (short*)(smem + 8192);         // 128*32 shorts
    const int g = blockIdx.x - GWG;
    const int wm = (wave >> 1) * 64, wn = (wave & 1) * 64;
    for (int item = g; item < 4096; item += PWG){
      const int bm = item >> 5, bn = item & 31;   // bm-major: early timesteps first
      floatx4 acc[4][4] = {};
      const short* Abase = Xb + (size_t)bm * 128 * K_SZ;
      const short* Bbase = Ub + (size_t)bn * 128 * K_SZ;
      for (int k0 = 0; k0 < K_SZ; k0 += 32){
#pragma unroll
        for (int i = 0; i < 2; ++i){
          int r0 = (wave * 2 + i) * 16;
          int row = r0 + (lane >> 2);
          int cof = (lane & 3) * 8;
          __builtin_amdgcn_global_load_lds(
            (const __attribute__((address_space(1))) void*)(Abase + (size_t)row * K_SZ + k0 + cof),
            (__attribute__((address_space(3))) void*)(As + r0 * 32), 16, 0, 0);
          __builtin_amdgcn_global_load_lds(
            (const __attribute__((address_space(1))) void*)(Bbase + (size_t)row * K_SZ + k0 + cof),
            (__attribute__((address_space(3))) void*)(Bs + r0 * 32), 16, 0, 0);
        }
        __syncthreads();
        short8 af[4], bf[4];
#pragma unroll
        for (int mt = 0; mt < 4; ++mt) af[mt] = *(const short8*)&As[(wm + mt * 16 + ml) * 32 + lg * 8];
#pragma unroll
        for (int nt = 0; nt < 4; ++nt) bf[nt] = *(const short8*)&Bs[(wn + nt * 16 + ml) * 32 + lg * 8];
#pragma unroll
        for (int mt = 0; mt < 4; ++mt)
#pragma unroll
          for (int nt = 0; nt < 4; ++nt)
            acc[mt][nt] = __builtin_amdgcn_mfma_f32_16x16x32_bf16(af[mt], bf[nt], acc[mt][nt], 0, 0, 0);
        __syncthreads();
      }
      // epilogue: agent-scope (L3-visible) stores
#pragma unroll
      for (int mt = 0; mt < 4; ++mt){
#pragma unroll
        for (int nt = 0; nt < 4; ++nt){
          const int row0 = bm * 128 + wm + mt * 16 + lg * 4;
          const int col  = bn * 128 + wn + nt * 16 + ml;
#pragma unroll
          for (int r = 0; r < 4; ++r)
            __hip_atomic_store(&gates_pre[(size_t)(row0 + r) * NG + col],
                               f2bf(acc[mt][nt][r]),
                               __ATOMIC_RELAXED, __HIP_MEMORY_SCOPE_AGENT);
        }
      }
      asm volatile("s_waitcnt vmcnt(0)" ::: "memory");  // per-wave: stores acked at L3
      __syncthreads();                                  // all 4 waves acked
      if (tid == 0)
        __hip_atomic_fetch_add(gp_cnt + bm, 1u, __ATOMIC_RELAXED, __HIP_MEMORY_SCOPE_AGENT);
    }
    return;
  }

  // ================= consumer: LSTM recurrence =================
  short* Vs = (short*)smem;                         // 32 * LPAD shorts
  short* hS = (short*)(smem + 66048);               // 32 * LPAD shorts
  float* gatesS = (float*)(smem + 132096);          // 32 * GPADW floats

  const int wg = blockIdx.x;
  const int j0 = wg * 8;
  const int mt = wave >> 1, nt = wave & 1;     // wave -> 16x16 tile of the 32x32 gate slice

  // ---- init: V slice to LDS; bias + c to registers ----
#pragma unroll
  for (int i = 0; i < 16; ++i){
    int e = i * 2048 + tid * 8;                // 32768 shorts total
    int rr = e >> 10, cc = e & 1023;           // rr = g*8 + rloc
    int gg = rr >> 3, rloc = rr & 7;
    const short* src = Vb + (size_t)(gg * 1024 + j0 + rloc) * 1024 + cc;
    *(short8*)&Vs[rr * LPAD + cc] = *(const short8*)src;
  }
  const int b_own = tid >> 3, jj_own = tid & 7;
  float bias_i = bih[0 * 1024 + j0 + jj_own] + bhh[0 * 1024 + j0 + jj_own];
  float bias_f = bih[1 * 1024 + j0 + jj_own] + bhh[1 * 1024 + j0 + jj_own];
  float bias_g = bih[2 * 1024 + j0 + jj_own] + bhh[2 * 1024 + j0 + jj_own];
  float bias_o = bih[3 * 1024 + j0 + jj_own] + bhh[3 * 1024 + j0 + jj_own];
  float c_reg  = c0[b_own * 1024 + j0 + jj_own];
  __syncthreads();

  const size_t SBH = (size_t)S_LEN * B_SZ * H_SZ;
  const size_t BH  = (size_t)B_SZ * H_SZ;
  float* out_h  = out;
  float* out_hf = out + SBH;
  float* out_cf = out + SBH + BH;
  float* out_h2 = out + SBH + 2 * BH;
  float* out_c  = out + 2 * SBH + 2 * BH;

  // per-thread gates_pre fragment coords
  const int c_sl = nt * 16 + ml;                          // gate-slice column 0..31
  const int gcol = (c_sl >> 3) * 1024 + j0 + (c_sl & 7);  // column in 4096

  // wait for bm=0 of gates_pre (producers start concurrently; V-init overlapped most of it)
  while (__hip_atomic_load(gp_cnt, __ATOMIC_RELAXED, __HIP_MEMORY_SCOPE_AGENT) < 32u)
    __builtin_amdgcn_s_sleep(2);
  unsigned ready_hi = 0;    // gp_cnt[0..ready_hi] known complete

  // prefetch gates_pre for t=0
  unsigned short gpr0, gpr1, gpr2, gpr3;
  {
    const unsigned short* gp = gates_pre + (size_t)(0 * 32 + mt * 16 + lg * 4) * NG + gcol;
    gpr0 = gp[0]; gpr1 = gp[NG]; gpr2 = gp[2 * (size_t)NG]; gpr3 = gp[3 * (size_t)NG];
  }

  for (int t = 0; t < S_LEN; ++t){
    // ---- early readiness probe for next bm group (result consumed after publish) ----
    const unsigned want = (unsigned)(t >> 2) + 1u;
    const bool do_probe = (want < 128u) && (want > ready_hi);
    unsigned probev = 0;
    if (do_probe)
      probev = __hip_atomic_load(gp_cnt + want, __ATOMIC_RELAXED, __HIP_MEMORY_SCOPE_AGENT);

    // ---- stage h(t): sentinel-validated speculative loads -> regs -> LDS ----
    // Each thread owns 16 x 16B chunks (as 32 x 8B). Agent-scope loads bypass L2
    // (plain loads would cache the stale sentinel line -> livelock).
    {
      const unsigned short* hb = hh + (size_t)t * 32768;
      const unsigned long long* Pq =
        (const unsigned long long*)(hb + wave * 512 + lane * 8);
      unsigned long long r[32];
      unsigned pend = 0xFFFFFFFFu;
      do {
#pragma unroll
        for (int s = 0; s < 32; ++s)
          if (pend & (1u << s))
            r[s] = __hip_atomic_load(Pq + (s >> 1) * 512 + (s & 1),
                                     __ATOMIC_RELAXED, __HIP_MEMORY_SCOPE_AGENT);
        unsigned np = 0;
#pragma unroll
        for (int s = 0; s < 32; ++s)
          if (pend & (1u << s)){
            unsigned lo = (unsigned)r[s], hi = (unsigned)(r[s] >> 32);
            if (lo == SENT32 || hi == SENT32) np |= (1u << s);
          }
        pend = np;
      } while (__any(pend != 0));
#pragma unroll
      for (int i = 0; i < 16; ++i){
        int g = i * 2048 + wave * 512 + lane * 8;
        int rr = g >> 10, cc = g & 1023;
        unsigned long long a = r[2 * i], b = r[2 * i + 1];
        uintx4 v; v[0] = (unsigned)a; v[1] = (unsigned)(a >> 32);
        v[2] = (unsigned)b; v[3] = (unsigned)(b >> 32);
        *(uintx4*)&hS[rr * LPAD + cc] = v;
      }
    }
    // acc init from prefetched gates_pre (x@U^T)
    floatx4 acc0, acc1;
    acc0[0] = bf2f(gpr0); acc0[1] = bf2f(gpr1); acc0[2] = bf2f(gpr2); acc0[3] = bf2f(gpr3);
    acc1[0] = 0.f; acc1[1] = 0.f; acc1[2] = 0.f; acc1[3] = 0.f;
    __syncthreads();                    // hS ready (all waves' ds_writes done)
    // ---- K loop: gates[b][c] += sum_k h[b][k] * V[c][k] ----
    const int abase = (mt * 16 + ml) * LPAD + lg * 8;
    const int bbase = (nt * 16 + ml) * LPAD + lg * 8;
#pragma unroll
    for (int kk = 0; kk < 32; kk += 2){
      short8 a0 = *(const short8*)&hS[abase + kk * 32];
      short8 b0 = *(const short8*)&Vs[bbase + kk * 32];
      short8 a1 = *(const short8*)&hS[abase + kk * 32 + 32];
      short8 b1 = *(const short8*)&Vs[bbase + kk * 32 + 32];
      acc0 = __builtin_amdgcn_mfma_f32_16x16x32_bf16(a0, b0, acc0, 0, 0, 0);
      acc1 = __builtin_amdgcn_mfma_f32_16x16x32_bf16(a1, b1, acc1, 0, 0, 0);
    }
    acc0 += acc1;
#pragma unroll
    for (int r = 0; r < 4; ++r)
      gatesS[(mt * 16 + lg * 4 + r) * GPADW + c_sl] = acc0[r];
    __syncthreads();
    // ---- cell update: one (b, jj) per thread ----
    float hv, cv;
    {
      float gi = gatesS[b_own * GPADW + jj_own]      + bias_i;
      float gf = gatesS[b_own * GPADW + 8 + jj_own]  + bias_f;
      float gg = gatesS[b_own * GPADW + 16 + jj_own] + bias_g;
      float go = gatesS[b_own * GPADW + 24 + jj_own] + bias_o;
      float iv = sigm(gi), fv = sigm(gf), gv = tanh_f(gg), ov = sigm(go);
      cv = fv * c_reg + iv * gv;
      c_reg = cv;
      hv = ov * tanh_f(cv);
    }
    // ---- publish immediately: shfl-pack 4 bf16 -> 8B agent-scope store. No ack, no flag. ----
    if (t + 1 < S_LEN){
      unsigned u  = (unsigned)f2bf(hv);
      unsigned n1 = __shfl_down(u, 1);
      unsigned p  = u | (n1 << 16);             // bf16[jj], bf16[jj+1]
      unsigned p2 = __shfl_down(p, 2);          // bf16[jj+2], bf16[jj+3]
      if ((tid & 3) == 0){
        unsigned long long v = (unsigned long long)p | ((unsigned long long)p2 << 32);
        unsigned long long* dst =
          (unsigned long long*)(hh + (size_t)(t + 1) * 32768 + (size_t)b_own * 1024 + j0 + jj_own);
        __hip_atomic_store(dst, v, __ATOMIC_RELAXED, __HIP_MEMORY_SCOPE_AGENT);
      }
      // consume early probe; fall back to spin only if producers are behind (early steps)
      if (do_probe && probev >= 32u) ready_hi = want;
      const unsigned bmn = (unsigned)(t + 1) >> 2;
      if (bmn > ready_hi){
        while (__hip_atomic_load(gp_cnt + bmn, __ATOMIC_RELAXED, __HIP_MEMORY_SCOPE_AGENT) < 32u)
          __builtin_amdgcn_s_sleep(1);
        ready_hi = bmn;
      }
      // prefetch gates_pre for t+1 (in flight across out-stores + next staging)
      const unsigned short* gp = gates_pre + (size_t)((t + 1) * 32 + mt * 16 + lg * 4) * NG + gcol;
      gpr0 = gp[0]; gpr1 = gp[NG]; gpr2 = gp[2 * (size_t)NG]; gpr3 = gp[3 * (size_t)NG];
    }
    // ---- out-stores: off the publish path; plain stores ack at local L2 ----
    {
      size_t o = (size_t)t * BH + (size_t)b_own * H_SZ + (size_t)(j0 + jj_own);
      out_h[o]  = hv;
      out_h2[o] = hv;
      out_c[o]  = cv;
      if (t == S_LEN - 1){
        out_hf[b_own * H_SZ + j0 + jj_own] = hv;
        out_cf[b_own * H_SZ + j0 + jj_own] = cv;
      }
    }
  }
}

// ---------------- launch ----------------
// ws layout (bytes)
#define WS_FLG 0                                  // gp_cnt @2048
#define WS_HH  4096                               // h history: 513 * 64 KB
#define WS_XB  (4096 + 513 * 65536)               // X bf16: 32 MB
#define WS_UB  (WS_XB + 33554432)                 // U bf16: 8 MB
#define WS_VB  (WS_UB + 8388608)                  // V bf16: 8 MB
#define WS_GP  (WS_VB + 8388608)                  // gates_pre bf16: 134.2 MB

extern "C" void kernel_launch(void* const* d_in, const int* in_sizes, int n_in,
                              void* d_out, int out_size, void* d_ws, size_t ws_size,
                              hipStream_t stream) {
  const float* X   = (const float*)d_in[0];   // [512,32,1024]
  const float* h0  = (const float*)d_in[1];   // [32,1024]
  const float* c0  = (const float*)d_in[2];   // [32,1024]
  const float* U   = (const float*)d_in[3];   // [4096,1024]
  const float* V   = (const float*)d_in[4];   // [4096,1024]
  const float* bih = (const float*)d_in[5];
  const float* bhh = (const float*)d_in[6];
  float* out = (float*)d_out;
  char* ws = (char*)d_ws;

  unsigned* flags      = (unsigned*)(ws + WS_FLG);
  unsigned* gp_cnt     = (unsigned*)(ws + WS_FLG + 2048);
  unsigned short* hh   = (unsigned short*)(ws + WS_HH);
  unsigned short* Xb   = (unsigned short*)(ws + WS_XB);
  unsigned short* Ub   = (unsigned short*)(ws + WS_UB);
  unsigned short* Vb   = (unsigned short*)(ws + WS_VB);
  unsigned short* gates = (unsigned short*)(ws + WS_GP);

  cvt_bf16 <<<dim3(16384), 256, 0, stream>>>(X, Xb, 16777216);
  cvt_bf16 <<<dim3(4096),  256, 0, stream>>>(U, Ub, 4194304);
  cvt_bf16 <<<dim3(4096),  256, 0, stream>>>(V, Vb, 4194304);
  fill_sent<<<dim3(8192),  256, 0, stream>>>(hh);
  cvt_h0   <<<dim3(32),    256, 0, stream>>>(h0, hh, flags);
  fused    <<<dim3(GWG + PWG), 256, 0, stream>>>((const short*)Xb, (const short*)Ub, gates,
                                                 (const short*)Vb, bih, bhh, c0,
                                                 hh, gp_cnt, out);
}

// Round 5
// 2390.035 us; speedup vs baseline: 1.3678x; 1.3678x over previous
//
#include <hip/hip_runtime.h>

#define S_LEN 512
#define B_SZ  32
#define H_SZ  1024
#define NG    4096      // 4H
#define K_SZ  1024
#define GWG   128       // consumer (recurrence) workgroups
#define PWG   96        // producer (GEMM) workgroups
#define SENT32 0xFFC0FFC0u   // bf16 NaN pair: unreachable for any real h/h0

typedef __attribute__((ext_vector_type(8))) short short8;
typedef __attribute__((ext_vector_type(4))) float floatx4;
typedef __attribute__((ext_vector_type(4))) unsigned short ushort4v;
typedef __attribute__((ext_vector_type(4))) unsigned int uintx4;

// ---------------- helpers ----------------
__device__ __forceinline__ unsigned short f2bf(float f){
  unsigned u = __float_as_uint(f);
  u += 0x7fffu + ((u >> 16) & 1u);     // RNE; inputs are finite/normal
  return (unsigned short)(u >> 16);
}
__device__ __forceinline__ float bf2f(unsigned short u){
  return __uint_as_float(((unsigned)u) << 16);
}
__device__ __forceinline__ float sigm(float x){ return 1.f / (1.f + __expf(-x)); }
__device__ __forceinline__ float tanh_f(float x){
  float ax = fabsf(x);
  float e = __expf(-2.f * ax);
  float r = (1.f - e) / (1.f + e);
  return copysignf(r, x);
}
// coalesced 16B L2-bypass load (always-fresh from L3), 64-bit VGPR address form.
__device__ __forceinline__ void load16_sc(uintx4 &d, const unsigned short* p){
  asm volatile("global_load_dwordx4 %0, %1, off sc0 sc1"
               : "=v"(d) : "v"(p));
}
#define WAITV() do { asm volatile("s_waitcnt vmcnt(0)" ::: "memory"); \
                     __builtin_amdgcn_sched_barrier(0); } while(0)

// ---------------- fp32 -> bf16 conversion ----------------
__global__ __launch_bounds__(256) void cvt_bf16(const float* __restrict__ s,
                                                unsigned short* __restrict__ d, int n){
  int i = (blockIdx.x * 256 + threadIdx.x) * 4;
  if (i < n){
    float4 v = *(const float4*)(s + i);
    ushort4v o; o.x = f2bf(v.x); o.y = f2bf(v.y); o.z = f2bf(v.z); o.w = f2bf(v.w);
    *(ushort4v*)(d + i) = o;
  }
}

// sentinel-fill h history slots 1..512 (32 MB)
__global__ __launch_bounds__(256) void fill_sent(unsigned short* __restrict__ hh){
  size_t i = 32768 + ((size_t)blockIdx.x * 256 + threadIdx.x) * 8;
  uintx4 v; v[0] = SENT32; v[1] = SENT32; v[2] = SENT32; v[3] = SENT32;
  *(uintx4*)(hh + i) = v;
}

// h0 -> bf16 into hpub[0] in SLICE layout [slice][b][jj]; zero gp_cnt
__global__ __launch_bounds__(256) void cvt_h0(const float* __restrict__ s,
                                              unsigned short* __restrict__ d,
                                              unsigned* __restrict__ flags){
  int i = (blockIdx.x * 256 + threadIdx.x) * 4;   // grid covers exactly 32768
  int b = i >> 10, j = i & 1023;                  // src = h0[b][j]
  float4 v = *(const float4*)(s + i);
  ushort4v o; o.x = f2bf(v.x); o.y = f2bf(v.y); o.z = f2bf(v.z); o.w = f2bf(v.w);
  *(ushort4v*)(d + (j >> 3) * 256 + b * 8 + (j & 7)) = o;
  if (blockIdx.x == 0){
    flags[512 + threadIdx.x] = 0u;     // gp_cnt (128 uints) + slack
  }
}

// ---------------- fused persistent kernel ----------------
// WGs [0,128): LSTM recurrence (1/CU). WGs [128,224): Phase-A GEMM producers.
// h exchange: contiguous 512B per-WG slices, sentinel-validated MFMA-fragment loads.
#define LPAD 1032
#define GPADW 36
__global__ __launch_bounds__(256) void fused(const short* __restrict__ Xb,
                                             const short* __restrict__ Ub,
                                             unsigned short* __restrict__ gates_pre,
                                             const short* __restrict__ Vb,
                                             const float* __restrict__ bih,
                                             const float* __restrict__ bhh,
                                             const float* __restrict__ c0,
                                             unsigned short* __restrict__ hh,   // hpub: 513 x [128][32][8] bf16
                                             unsigned* __restrict__ gp_cnt,     // 128 uints
                                             float* __restrict__ out){
  __shared__ alignas(16) char smem[75264];
  const int tid = threadIdx.x;
  const int wave = tid >> 6, lane = tid & 63;
  const int ml = lane & 15, lg = lane >> 4;

  if (blockIdx.x >= GWG){
    // ================= producer: gates_pre[M=16384,4096] = Xb @ Ub^T =================
    short* As = (short*)smem;                  // 128*32 shorts
    short* Bs = (short*)(smem + 8192);         // 128*32 shorts
    const int g = blockIdx.x - GWG;
    const int wm = (wave >> 1) * 64, wn = (wave & 1) * 64;
    for (int item = g; item < 4096; item += PWG){
      const int bm = item >> 5, bn = item & 31;   // bm-major: early timesteps first
      floatx4 acc[4][4] = {};
      const short* Abase = Xb + (size_t)bm * 128 * K_SZ;
      const short* Bbase = Ub + (size_t)bn * 128 * K_SZ;
      for (int k0 = 0; k0 < K_SZ; k0 += 32){
#pragma unroll
        for (int i = 0; i < 2; ++i){
          int r0 = (wave * 2 + i) * 16;
          int row = r0 + (lane >> 2);
          int cof = (lane & 3) * 8;
          __builtin_amdgcn_global_load_lds(
            (const __attribute__((address_space(1))) void*)(Abase + (size_t)row * K_SZ + k0 + cof),
            (__attribute__((address_space(3))) void*)(As + r0 * 32), 16, 0, 0);
          __builtin_amdgcn_global_load_lds(
            (const __attribute__((address_space(1))) void*)(Bbase + (size_t)row * K_SZ + k0 + cof),
            (__attribute__((address_space(3))) void*)(Bs + r0 * 32), 16, 0, 0);
        }
        __syncthreads();
        short8 af[4], bf[4];
#pragma unroll
        for (int mt = 0; mt < 4; ++mt) af[mt] = *(const short8*)&As[(wm + mt * 16 + ml) * 32 + lg * 8];
#pragma unroll
        for (int nt = 0; nt < 4; ++nt) bf[nt] = *(const short8*)&Bs[(wn + nt * 16 + ml) * 32 + lg * 8];
#pragma unroll
        for (int mt = 0; mt < 4; ++mt)
#pragma unroll
          for (int nt = 0; nt < 4; ++nt)
            acc[mt][nt] = __builtin_amdgcn_mfma_f32_16x16x32_bf16(af[mt], bf[nt], acc[mt][nt], 0, 0, 0);
        __syncthreads();
      }
#pragma unroll
      for (int mt = 0; mt < 4; ++mt){
#pragma unroll
        for (int nt = 0; nt < 4; ++nt){
          const int row0 = bm * 128 + wm + mt * 16 + lg * 4;
          const int col  = bn * 128 + wn + nt * 16 + ml;
#pragma unroll
          for (int r = 0; r < 4; ++r)
            __hip_atomic_store(&gates_pre[(size_t)(row0 + r) * NG + col],
                               f2bf(acc[mt][nt][r]),
                               __ATOMIC_RELAXED, __HIP_MEMORY_SCOPE_AGENT);
        }
      }
      asm volatile("s_waitcnt vmcnt(0)" ::: "memory");  // stores acked at L3
      __syncthreads();
      if (tid == 0)
        __hip_atomic_fetch_add(gp_cnt + bm, 1u, __ATOMIC_RELAXED, __HIP_MEMORY_SCOPE_AGENT);
    }
    return;
  }

  // ================= consumer: LSTM recurrence =================
  short* Vs = (short*)smem;                         // 32 * LPAD shorts (66048 B)
  float* gatesS = (float*)(smem + 66048);           // [2][32][GPADW] floats (9216 B)

  const int wg = blockIdx.x;
  const int j0 = wg * 8;
  const int mt = wave >> 1;        // batch-half (b 0-15 / 16-31)
  const int kh = wave & 1;         // K-half (kk 0-15 / 16-31)

  // ---- init: V slice to LDS; bias + c to registers ----
#pragma unroll
  for (int i = 0; i < 16; ++i){
    int e = i * 2048 + tid * 8;                // 32768 shorts total
    int rr = e >> 10, cc = e & 1023;
    int gg = rr >> 3, rloc = rr & 7;
    const short* src = Vb + (size_t)(gg * 1024 + j0 + rloc) * 1024 + cc;
    *(short8*)&Vs[rr * LPAD + cc] = *(const short8*)src;
  }
  const int b_own = tid >> 3, jj_own = tid & 7;
  float bias_i = bih[0 * 1024 + j0 + jj_own] + bhh[0 * 1024 + j0 + jj_own];
  float bias_f = bih[1 * 1024 + j0 + jj_own] + bhh[1 * 1024 + j0 + jj_own];
  float bias_g = bih[2 * 1024 + j0 + jj_own] + bhh[2 * 1024 + j0 + jj_own];
  float bias_o = bih[3 * 1024 + j0 + jj_own] + bhh[3 * 1024 + j0 + jj_own];
  float c_reg  = c0[b_own * 1024 + j0 + jj_own];
  __syncthreads();

  const size_t SBH = (size_t)S_LEN * B_SZ * H_SZ;
  const size_t BH  = (size_t)B_SZ * H_SZ;
  float* out_h  = out;
  float* out_hf = out + SBH;
  float* out_cf = out + SBH + BH;
  float* out_h2 = out + SBH + 2 * BH;
  float* out_c  = out + 2 * SBH + 2 * BH;

  const int row0  = mt * 16 + lg * 4;                      // gate row (batch) base
  const int gcol0 = (ml >> 3) * 1024 + j0 + (ml & 7);      // col ml  (gates 0/1)
  // A-fragment element offset: slice(kk*4+lg)*256 + b*8 shorts; kk = kh*16 + j
  const int eoff0 = kh * 16384 + lg * 256 + (mt * 16 + ml) * 8;

  // wait for bm=0 of gates_pre
  while (__hip_atomic_load(gp_cnt, __ATOMIC_RELAXED, __HIP_MEMORY_SCOPE_AGENT) < 32u)
    __builtin_amdgcn_s_sleep(2);
  unsigned ready_hi = 0;

  // prefetch gates_pre for t=0 (kh==0 waves carry the x@U^T init)
  unsigned short gpr[8];
  if (kh == 0){
    const unsigned short* gp = gates_pre + (size_t)(0 * 32 + row0) * NG + gcol0;
#pragma unroll
    for (int r = 0; r < 4; ++r){ gpr[r] = gp[(size_t)r * NG]; gpr[4 + r] = gp[(size_t)r * NG + 2048]; }
  }
  // issue A-fragment loads for t=0 (hpub[0] from cvt_h0)
  uintx4 a[16];
#pragma unroll
  for (int j = 0; j < 16; ++j) load16_sc(a[j], hh + eoff0 + j * 1024);

  for (int t = 0; t < S_LEN; ++t){
    // early readiness probe for next bm group
    const unsigned want = (unsigned)(t >> 2) + 1u;
    const bool do_probe = (want < 128u) && (want > ready_hi);
    unsigned probev = 0;
    if (do_probe)
      probev = __hip_atomic_load(gp_cnt + want, __ATOMIC_RELAXED, __HIP_MEMORY_SCOPE_AGENT);

    // ---- validate speculative A-fragments; retry only pending slices ----
    const unsigned short* hpt = hh + (size_t)t * 32768;
    WAITV();
    unsigned pend = 0;
#pragma unroll
    for (int j = 0; j < 16; ++j)
      if (a[j][0] == SENT32 || a[j][2] == SENT32) pend |= (1u << j);
    while (__any(pend != 0)){
#pragma unroll
      for (int j = 0; j < 16; ++j)
        if (pend & (1u << j)) load16_sc(a[j], hpt + eoff0 + j * 1024);
      WAITV();
      unsigned np = 0;
#pragma unroll
      for (int j = 0; j < 16; ++j)
        if ((pend & (1u << j)) && (a[j][0] == SENT32 || a[j][2] == SENT32)) np |= (1u << j);
      pend = np;
    }

    // ---- acc init (x@U^T added once, by kh==0 waves) ----
    floatx4 acc0, acc1;    // col tiles 0-15 / 16-31
    if (kh == 0){
#pragma unroll
      for (int r = 0; r < 4; ++r){ acc0[r] = bf2f(gpr[r]); acc1[r] = bf2f(gpr[4 + r]); }
    } else {
#pragma unroll
      for (int r = 0; r < 4; ++r){ acc0[r] = 0.f; acc1[r] = 0.f; }
    }
    // ---- K-half MFMA: gates[b][c] += sum_k h[b][k] * V[c][k] ----
    const int vb0 = ml * LPAD + lg * 8;
    const int vb1 = (16 + ml) * LPAD + lg * 8;
#pragma unroll
    for (int j = 0; j < 16; ++j){
      const int kk = kh * 16 + j;
      short8 av = __builtin_bit_cast(short8, a[j]);
      short8 v0 = *(const short8*)&Vs[vb0 + kk * 32];
      short8 v1 = *(const short8*)&Vs[vb1 + kk * 32];
      acc0 = __builtin_amdgcn_mfma_f32_16x16x32_bf16(av, v0, acc0, 0, 0, 0);
      acc1 = __builtin_amdgcn_mfma_f32_16x16x32_bf16(av, v1, acc1, 0, 0, 0);
    }
    __syncthreads();     // B2: all prev-step gatesS reads done (WAR)
#pragma unroll
    for (int r = 0; r < 4; ++r){
      float* gr = gatesS + (size_t)(kh * 32 + row0 + r) * GPADW;
      gr[ml]      = acc0[r];
      gr[16 + ml] = acc1[r];
    }
    __syncthreads();     // B1: partial sums visible
    // ---- cell update: one (b, jj) per thread; sum the two K-half planes ----
    float hv, cv;
    {
      const float* g0 = gatesS + (size_t)b_own * GPADW;
      const float* g1 = gatesS + (size_t)(32 + b_own) * GPADW;
      float gi = g0[jj_own]      + g1[jj_own]      + bias_i;
      float gf = g0[8 + jj_own]  + g1[8 + jj_own]  + bias_f;
      float gg = g0[16 + jj_own] + g1[16 + jj_own] + bias_g;
      float go = g0[24 + jj_own] + g1[24 + jj_own] + bias_o;
      float iv = sigm(gi), fv = sigm(gf), gv = tanh_f(gg), ov = sigm(go);
      cv = fv * c_reg + iv * gv;
      c_reg = cv;
      hv = ov * tanh_f(cv);
    }
    if (t + 1 < S_LEN){
      // ---- publish h(t+1) slice: shfl-pack 4 bf16 -> 8B sc store, contiguous slice ----
      unsigned u  = (unsigned)f2bf(hv);
      unsigned n1 = __shfl_down(u, 1);
      unsigned p  = u | (n1 << 16);
      unsigned p2 = __shfl_down(p, 2);
      if ((tid & 3) == 0){
        unsigned long long v = (unsigned long long)p | ((unsigned long long)p2 << 32);
        unsigned long long* dst =
          (unsigned long long*)(hh + (size_t)(t + 1) * 32768 + wg * 256 + b_own * 8 + jj_own);
        __hip_atomic_store(dst, v, __ATOMIC_RELAXED, __HIP_MEMORY_SCOPE_AGENT);
      }
      // ---- issue speculative A-loads for t+1 (validated at next loop top) ----
      const unsigned short* hpn = hh + (size_t)(t + 1) * 32768;
#pragma unroll
      for (int j = 0; j < 16; ++j) load16_sc(a[j], hpn + eoff0 + j * 1024);
      // gates_pre readiness
      if (do_probe && probev >= 32u) ready_hi = want;
      const unsigned bmn = (unsigned)(t + 1) >> 2;
      if (bmn > ready_hi){
        while (__hip_atomic_load(gp_cnt + bmn, __ATOMIC_RELAXED, __HIP_MEMORY_SCOPE_AGENT) < 32u)
          __builtin_amdgcn_s_sleep(1);
        ready_hi = bmn;
      }
      // prefetch gates_pre for t+1
      if (kh == 0){
        const unsigned short* gp = gates_pre + (size_t)((t + 1) * 32 + row0) * NG + gcol0;
#pragma unroll
        for (int r = 0; r < 4; ++r){ gpr[r] = gp[(size_t)r * NG]; gpr[4 + r] = gp[(size_t)r * NG + 2048]; }
      }
    }
    // ---- out-stores: off the critical path; plain stores ack at local L2 ----
    {
      size_t o = (size_t)t * BH + (size_t)b_own * H_SZ + (size_t)(j0 + jj_own);
      out_h[o]  = hv;
      out_h2[o] = hv;
      out_c[o]  = cv;
      if (t == S_LEN - 1){
        out_hf[b_own * H_SZ + j0 + jj_own] = hv;
        out_cf[b_own * H_SZ + j0 + jj_own] = cv;
      }
    }
  }
}

// ---------------- launch ----------------
// ws layout (bytes)
#define WS_FLG 0                                  // gp_cnt @2048
#define WS_HH  4096                               // hpub: 513 * 64 KB
#define WS_XB  (4096 + 513 * 65536)               // X bf16: 32 MB
#define WS_UB  (WS_XB + 33554432)                 // U bf16: 8 MB
#define WS_VB  (WS_UB + 8388608)                  // V bf16: 8 MB
#define WS_GP  (WS_VB + 8388608)                  // gates_pre bf16: 134.2 MB

extern "C" void kernel_launch(void* const* d_in, const int* in_sizes, int n_in,
                              void* d_out, int out_size, void* d_ws, size_t ws_size,
                              hipStream_t stream) {
  const float* X   = (const float*)d_in[0];   // [512,32,1024]
  const float* h0  = (const float*)d_in[1];   // [32,1024]
  const float* c0  = (const float*)d_in[2];   // [32,1024]
  const float* U   = (const float*)d_in[3];   // [4096,1024]
  const float* V   = (const float*)d_in[4];   // [4096,1024]
  const float* bih = (const float*)d_in[5];
  const float* bhh = (const float*)d_in[6];
  float* out = (float*)d_out;
  char* ws = (char*)d_ws;

  unsigned* flags      = (unsigned*)(ws + WS_FLG);
  unsigned* gp_cnt     = (unsigned*)(ws + WS_FLG + 2048);
  unsigned short* hh   = (unsigned short*)(ws + WS_HH);
  unsigned short* Xb   = (unsigned short*)(ws + WS_XB);
  unsigned short* Ub   = (unsigned short*)(ws + WS_UB);
  unsigned short* Vb   = (unsigned short*)(ws + WS_VB);
  unsigned short* gates = (unsigned short*)(ws + WS_GP);

  cvt_bf16 <<<dim3(16384), 256, 0, stream>>>(X, Xb, 16777216);
  cvt_bf16 <<<dim3(4096),  256, 0, stream>>>(U, Ub, 4194304);
  cvt_bf16 <<<dim3(4096),  256, 0, stream>>>(V, Vb, 4194304);
  fill_sent<<<dim3(8192),  256, 0, stream>>>(hh);
  cvt_h0   <<<dim3(32),    256, 0, stream>>>(h0, hh, flags);
  fused    <<<dim3(GWG + PWG), 256, 0, stream>>>((const short*)Xb, (const short*)Ub, gates,
                                                 (const short*)Vb, bih, bhh, c0,
                                                 hh, gp_cnt, out);
}